// Round 13
// baseline (265.109 us; speedup 1.0000x reference)
//
#include <hip/hip_runtime.h>
#include <hip/hip_bf16.h>

#define LSEQ 2048
#define NH 16
#define HS 64
#define DIM 1024

typedef __attribute__((ext_vector_type(8))) short short8;
typedef __attribute__((ext_vector_type(4))) float f32x4;

typedef const __attribute__((address_space(1))) void g_void_t;
typedef __attribute__((address_space(3))) void s_void_t;

// 0.125 (1/sqrt(hs)) * log2(e): folded into Q so softmax runs in base 2.
#define QSCALE 0.18033688011112042f
#define PART_BYTES 17408   // [128][64] bf16 O-unnorm + f32 m[128] + f32 l[128]

static __device__ __forceinline__ short f2bf(float f) {
  __hip_bfloat16 h = __float2bfloat16(f);
  return __builtin_bit_cast(short, h);
}
static __device__ __forceinline__ float bf2f(short s) {
  __hip_bfloat16 h = __builtin_bit_cast(__hip_bfloat16, s);
  return __bfloat162float(h);
}

static __device__ __forceinline__ float fexp2(float x) {
#if __has_builtin(__builtin_amdgcn_exp2f)
  return __builtin_amdgcn_exp2f(x);
#else
  float r; asm("v_exp_f32 %0, %1" : "=v"(r) : "v"(x)); return r;
#endif
}

// DPP cross-lane move (VALU-only, no LDS pipe).
template<int CTRL>
static __device__ __forceinline__ float dpp_mov(float x) {
  return __builtin_bit_cast(float,
      __builtin_amdgcn_update_dpp(0, __builtin_bit_cast(int, x), CTRL, 0xF, 0xF, true));
}
// Butterfly over 16-lane group with independent masks:
// quad_perm[1,0,3,2]=0xB1, quad_perm[2,3,0,1]=0x4E, row_half_mirror=0x141, row_mirror=0x140.
static __device__ __forceinline__ float redmax16(float x) {
  x = fmaxf(x, dpp_mov<0xB1>(x));
  x = fmaxf(x, dpp_mov<0x4E>(x));
  x = fmaxf(x, dpp_mov<0x141>(x));
  x = fmaxf(x, dpp_mov<0x140>(x));
  return x;
}
static __device__ __forceinline__ float redsum16(float x) {
  x += dpp_mov<0xB1>(x);
  x += dpp_mov<0x4E>(x);
  x += dpp_mov<0x141>(x);
  x += dpp_mov<0x140>(x);
  return x;
}

// ---------------- fused prep kernel (x-cast, Er-cast, Wqkv^T, Wproj^T) ----------------

__global__ void prep_kernel(const float* __restrict__ x, const float* __restrict__ Er,
                            const float* __restrict__ Wqkv, const float* __restrict__ Wproj,
                            short* __restrict__ xb, short* __restrict__ Erb,
                            short* __restrict__ WqkvT, short* __restrict__ WprojT) {
  __shared__ float tile[64][65];
  int bid = blockIdx.x;
  if (bid < 4224) {
    const float* in; short* out; int i0;
    if (bid < 4096) { in = x;  out = xb;  i0 = bid * 256; }
    else            { in = Er; out = Erb; i0 = (bid - 4096) * 256; }
    int i = i0 + threadIdx.x;
    float4 v = reinterpret_cast<const float4*>(in)[i];
    short4 o;
    o.x = f2bf(v.x); o.y = f2bf(v.y); o.z = f2bf(v.z); o.w = f2bf(v.w);
    reinterpret_cast<short4*>(out)[i] = o;
    return;
  }
  int id = bid - 4224;
  const float* W; short* Wt; int N, tx, ty;
  if (id < 768) { W = Wqkv;  Wt = WqkvT;  N = 3072; tx = id % 48; ty = id / 48; }
  else { id -= 768; W = Wproj; Wt = WprojT; N = 1024; tx = id % 16; ty = id / 16; }
  const int K = 1024;
  int k0 = ty * 64, n0 = tx * 64;
  int t = threadIdx.x;
  int r4 = t >> 6, cc = t & 63;
  for (int i = 0; i < 16; ++i) {
    int row = i * 4 + r4;
    tile[row][cc] = W[(size_t)(k0 + row) * N + (n0 + cc)];
  }
  __syncthreads();
  for (int i = 0; i < 16; ++i) {
    int row = i * 4 + r4;
    Wt[(size_t)(n0 + row) * K + (k0 + cc)] = f2bf(tile[cc][row]);
  }
}

// ---------------- GEMM1 (A[M][K] bf16 row-major, Bt[N][K] bf16 row-major) ----------------

__global__ __launch_bounds__(256, 3) void gemm1_kernel(
    const short* __restrict__ A, const short* __restrict__ Bt,
    const float* __restrict__ bias, int M, int N, int K,
    short* __restrict__ oq, short* __restrict__ ok, short* __restrict__ ov)
{
  __shared__ short Al[128 * 32];
  __shared__ short Bl[128 * 32];
  const int m0 = blockIdx.y * 128, n0 = blockIdx.x * 128;
  const int t = threadIdx.x;
  const int lane = t & 63, wave = t >> 6;
  const int wr = wave >> 1, wc = wave & 1;
  const int g = lane >> 4, c = lane & 15;
  f32x4 acc[4][4] = {};

  for (int k0 = 0; k0 < K; k0 += 32) {
    __syncthreads();
    for (int i = 0; i < 2; ++i) {
      int ch = i * 256 + t;
      int row = ch >> 2, c8 = ch & 3;
      __builtin_amdgcn_global_load_lds(
          (g_void_t*)(A + (size_t)(m0 + row) * K + k0 + c8 * 8),
          (s_void_t*)(Al + (i * 256 + wave * 64) * 8), 16, 0, 0);
      __builtin_amdgcn_global_load_lds(
          (g_void_t*)(Bt + (size_t)(n0 + row) * K + k0 + c8 * 8),
          (s_void_t*)(Bl + (i * 256 + wave * 64) * 8), 16, 0, 0);
    }
    __syncthreads();
    short8 af[4], bf[4];
#pragma unroll
    for (int mi = 0; mi < 4; ++mi) {
      int row = wr * 64 + mi * 16 + c;
      af[mi] = *reinterpret_cast<const short8*>(Al + row * 32 + g * 8);
    }
#pragma unroll
    for (int ni = 0; ni < 4; ++ni) {
      int row = wc * 64 + ni * 16 + c;
      bf[ni] = *reinterpret_cast<const short8*>(Bl + row * 32 + g * 8);
    }
#pragma unroll
    for (int mi = 0; mi < 4; ++mi)
#pragma unroll
      for (int ni = 0; ni < 4; ++ni)
        acc[mi][ni] = __builtin_amdgcn_mfma_f32_16x16x32_bf16(af[mi], bf[ni], acc[mi][ni], 0, 0, 0);
  }

#pragma unroll
  for (int mi = 0; mi < 4; ++mi)
#pragma unroll
    for (int ni = 0; ni < 4; ++ni) {
      int n = n0 + wc * 64 + ni * 16 + c;
      float bv = bias[n];
#pragma unroll
      for (int r = 0; r < 4; ++r) {
        int m = m0 + wr * 64 + mi * 16 + g * 4 + r;
        float val = acc[mi][ni][r] + bv;
        int which = n >> 10;
        int hh2 = (n >> 6) & 15;
        int d = n & 63;
        int b = m >> 11, ll = m & 2047;
        if (which == 0) {
          oq[(((size_t)b * NH + hh2) * LSEQ + ll) * HS + d] = f2bf(val * QSCALE);
        } else if (which == 1) {
          ok[(((size_t)b * NH + hh2) * LSEQ + ll) * HS + d] = f2bf(val);
        } else {
          ov[(((size_t)b * NH + hh2) * HS + d) * LSEQ + ll] = f2bf(val);
        }
      }
    }
}

// ---------------- GEMM2: 64x128 tile -> 512 wgs (2/CU co-resident) ----------------

__global__ __launch_bounds__(256, 4) void gemm2_kernel(
    const short* __restrict__ A, const short* __restrict__ Bt,
    const float* __restrict__ bias, float* __restrict__ of)
{
  __shared__ short Al[64 * 32];
  __shared__ short Bl[128 * 32];
  const int K = 1024, N = 1024;
  const int m0 = blockIdx.y * 64, n0 = blockIdx.x * 128;
  const int t = threadIdx.x;
  const int lane = t & 63, wave = t >> 6;
  const int wm = wave & 1, wn = wave >> 1;
  const int g = lane >> 4, c = lane & 15;
  f32x4 acc[2][4] = {};

  for (int k0 = 0; k0 < K; k0 += 32) {
    __syncthreads();
    {
      int row = t >> 2, c8 = t & 3;
      __builtin_amdgcn_global_load_lds(
          (g_void_t*)(A + (size_t)(m0 + row) * K + k0 + c8 * 8),
          (s_void_t*)(Al + wave * 512), 16, 0, 0);
    }
    for (int i = 0; i < 2; ++i) {
      int ch = i * 256 + t;
      int row = ch >> 2, c8 = ch & 3;
      __builtin_amdgcn_global_load_lds(
          (g_void_t*)(Bt + (size_t)(n0 + row) * K + k0 + c8 * 8),
          (s_void_t*)(Bl + (i * 256 + wave * 64) * 8), 16, 0, 0);
    }
    __syncthreads();
    short8 af[2], bf[4];
#pragma unroll
    for (int mi = 0; mi < 2; ++mi) {
      int row = wm * 32 + mi * 16 + c;
      af[mi] = *reinterpret_cast<const short8*>(Al + row * 32 + g * 8);
    }
#pragma unroll
    for (int ni = 0; ni < 4; ++ni) {
      int row = wn * 64 + ni * 16 + c;
      bf[ni] = *reinterpret_cast<const short8*>(Bl + row * 32 + g * 8);
    }
#pragma unroll
    for (int mi = 0; mi < 2; ++mi)
#pragma unroll
      for (int ni = 0; ni < 4; ++ni)
        acc[mi][ni] = __builtin_amdgcn_mfma_f32_16x16x32_bf16(af[mi], bf[ni], acc[mi][ni], 0, 0, 0);
  }

#pragma unroll
  for (int mi = 0; mi < 2; ++mi)
#pragma unroll
    for (int ni = 0; ni < 4; ++ni) {
      int n = n0 + wn * 64 + ni * 16 + c;
      float bv = bias[n];
#pragma unroll
      for (int r = 0; r < 4; ++r) {
        int m = m0 + wm * 32 + mi * 16 + g * 4 + r;
        of[(size_t)m * N + n] = acc[mi][ni][r] + bv;
      }
    }
}

// ---------------- fused flash attention with relative-position band ----------------
// R11-proven (passed, 77.6us): 32-rows-per-wave compute, equal 17-step wgs via
// k-split of heavy tiles. NEW: the flash-decode merge is folded in-kernel —
// both halves write partials, fence, lane0 atomicAdd on a per-sp counter
// (zeroed each launch by hipMemsetAsync), the SECOND finisher acquires and
// merges. Removes the merge kernel launch; merge overlaps the attn tail.

__global__ __launch_bounds__(256, 2) void attn_kernel(
    const short* __restrict__ Qb, const short* __restrict__ Kb,
    const short* __restrict__ VTb, const short* __restrict__ Erb,
    short* __restrict__ Y, char* __restrict__ Part, unsigned* __restrict__ Cnt)
{
  const int bid = blockIdx.x;
  const int jid = bid >> 5;        // 0..15
  const int bh = bid & 31;
  const int p = jid >> 1;          // 0..7
  const int half = jid & 1;
  const int bb = bh >> 4, hh = bh & 15;
  const int t = threadIdx.x;
  const int lane = t & 63, w = t >> 6;   // wave 0..3
  const int g = lane >> 4, c = lane & 15;
  const int r8 = lane >> 3;
  const int c16b = (lane & 7) * 16;

  __shared__ short Kl[2][64 * 64];       // 16 KB dbuf
  __shared__ short Vl[2][64 * 64];       // 16 KB dbuf (V^T rows = d)
  __shared__ short El[4][64 * 64];       // 32 KB circular, slot = chunk & 3
  __shared__ short Pl[4][32 * 64];       // 16 KB per-wave P (32 rows)
  __shared__ unsigned oldsh;

  auto stage_KV = [&](int step, int sel) {
#pragma unroll
    for (int jj = 0; jj < 2; ++jj) {
      int rr = w * 16 + jj * 8 + r8;
      const char* Kg = (const char*)(Kb + ((size_t)bh * LSEQ + step * 64) * HS);
      __builtin_amdgcn_global_load_lds(
          (g_void_t*)(Kg + rr * 128 + (c16b ^ ((rr & 7) << 4))),
          (s_void_t*)(&Kl[sel][(w * 16 + jj * 8) * 64]), 16, 0, 0);
    }
#pragma unroll
    for (int jj = 0; jj < 2; ++jj) {
      int rr = w * 16 + jj * 8 + r8;     // d index
      const char* Vg = (const char*)(VTb + ((size_t)bh * HS + rr) * LSEQ + step * 64);
      __builtin_amdgcn_global_load_lds(
          (g_void_t*)(Vg + (c16b ^ ((rr & 7) << 4))),
          (s_void_t*)(&Vl[sel][(w * 16 + jj * 8) * 64]), 16, 0, 0);
    }
  };
  auto stage_E = [&](int chunk) {
    int slot = chunk & 3;
#pragma unroll
    for (int jj = 0; jj < 2; ++jj) {
      int rr = w * 16 + jj * 8 + r8;     // local row 0..63
      int e = chunk * 64 + rr;
      if (e > LSEQ - 1) e = LSEQ - 1;    // clamped rows feed masked cols only
      if (e < 0) e = 0;
      __builtin_amdgcn_global_load_lds(
          (g_void_t*)((const char*)Erb + (size_t)e * 128 + (c16b ^ ((rr & 7) << 4))),
          (s_void_t*)(&El[slot][(w * 16 + jj * 8) * 64]), 16, 0, 0);
    }
  };

  // process one 128-row q-tile's k-steps [s0, s1)
  auto process = [&](int qt, int s0, int s1, bool direct, int pslot) {
    const int l0 = qt * 128;
    const int c00 = 31 - 2 * qt;         // R7-verified Er chunk base
    const int nsteps = 2 * qt + 2;

    short8 qf[2][2];
#pragma unroll
    for (int tt = 0; tt < 2; ++tt)
#pragma unroll
      for (int kk = 0; kk < 2; ++kk)
        qf[tt][kk] = *reinterpret_cast<const short8*>(
            Qb + ((size_t)bh * LSEQ + l0 + w * 32 + tt * 16 + c) * HS + kk * 32 + g * 8);

    stage_KV(s0, s0 & 1);
    stage_E(c00 + s0 - 1); stage_E(c00 + s0); stage_E(c00 + s0 + 1);

    f32x4 acc_o[2][4] = {};
    float mrun[2][4], lrun[2][4];
#pragma unroll
    for (int tt = 0; tt < 2; ++tt)
#pragma unroll
      for (int r = 0; r < 4; ++r) { mrun[tt][r] = -1e30f; lrun[tt][r] = 0.0f; }

    for (int s = s0; s < s1; ++s) {
      const int sel = s & 1;
      const int c0 = c00 + s;

      if (s + 1 < s1) {
        stage_KV(s + 1, sel ^ 1);        // safe: bottom barrier of s-1 passed
        stage_E(c0 + 2);                 // slot (c0+2)&3 == (c0-2)&3, free
        asm volatile("s_waitcnt vmcnt(6)" ::: "memory");
      } else {
        asm volatile("s_waitcnt vmcnt(0)" ::: "memory");
      }
      __builtin_amdgcn_s_barrier();
      __builtin_amdgcn_sched_barrier(0);

      // last step of the tile: waves 0,1 (rows < 64) fully causally masked
      const bool deadwave = (s == nsteps - 1) && (w < 2);
      if (!deadwave) {
        const bool maskstep = (s >= 2 * qt);

        __builtin_amdgcn_s_setprio(1);
        // ---- G = Q · ErBand^T: 6 shared windows, 10 output tiles ----
        f32x4 ga[2][5];
#pragma unroll
        for (int tt = 0; tt < 2; ++tt)
#pragma unroll
          for (int s5 = 0; s5 < 5; ++s5) ga[tt][s5] = (f32x4){0.0f, 0.0f, 0.0f, 0.0f};
#pragma unroll
        for (int u = 0; u < 6; ++u) {
          int rb = ((2 - 2 * w) + u) * 16 + c;   // signed band row -64..126
          int chunk = c0 + (rb >> 6);            // arithmetic shift
          int phys = ((chunk & 3) << 6) | (rb & 63);
#pragma unroll
          for (int kk = 0; kk < 2; ++kk) {
            int byte = phys * 128 + (((kk * 32 + g * 8) * 2) ^ ((rb & 7) << 4));
            short8 ef = *reinterpret_cast<const short8*>((char*)El + byte);
            if (u >= 1) ga[0][u - 1] = __builtin_amdgcn_mfma_f32_16x16x32_bf16(qf[0][kk], ef, ga[0][u - 1], 0, 0, 0);
            if (u <= 4) ga[1][u]     = __builtin_amdgcn_mfma_f32_16x16x32_bf16(qf[1][kk], ef, ga[1][u], 0, 0, 0);
          }
        }

        // ---- S = Q K^T (K-frag shared across both row-subtiles) ----
        f32x4 sa[2][4];
#pragma unroll
        for (int tt = 0; tt < 2; ++tt)
#pragma unroll
          for (int ns = 0; ns < 4; ++ns) sa[tt][ns] = (f32x4){0.0f, 0.0f, 0.0f, 0.0f};
#pragma unroll
        for (int ns = 0; ns < 4; ++ns) {
#pragma unroll
          for (int kk = 0; kk < 2; ++kk) {
            int row = ns * 16 + c;
            int byte = row * 128 + (((kk * 32 + g * 8) * 2) ^ ((row & 7) << 4));
            short8 kf = *reinterpret_cast<const short8*>((char*)Kl[sel] + byte);
            sa[0][ns] = __builtin_amdgcn_mfma_f32_16x16x32_bf16(qf[0][kk], kf, sa[0][ns], 0, 0, 0);
            sa[1][ns] = __builtin_amdgcn_mfma_f32_16x16x32_bf16(qf[1][kk], kf, sa[1][ns], 0, 0, 0);
          }
        }
        __builtin_amdgcn_s_setprio(0);

        // ---- skew + mask + online softmax per row-subtile ----
        float sv[2][4][4];
        bool need = false;
        float mx[2][4];
#pragma unroll
        for (int tt = 0; tt < 2; ++tt) {
#pragma unroll
          for (int r = 0; r < 4; ++r) {
            int i4 = g * 4 + r;
            int u0 = c + 15 - i4;            // 0..30
            int srcl = (g << 4) | (u0 & 15);
            float bp[5];
#pragma unroll
            for (int s5 = 0; s5 < 5; ++s5) bp[s5] = __shfl(ga[tt][s5][r], srcl, 64);
            bool lo = (u0 < 16);
            int thr = (l0 - 64 * s) + w * 32 + tt * 16 + i4;
#pragma unroll
            for (int ns = 0; ns < 4; ++ns) {
              float srel = lo ? bp[ns] : bp[ns + 1];
              float xx = sa[tt][ns][r] + srel;
              if (maskstep && (ns * 16 + c > thr)) xx = -1e30f;
              sv[tt][ns][r] = xx;
            }
          }
#pragma unroll
          for (int r = 0; r < 4; ++r) {
            float m = fmaxf(fmaxf(sv[tt][0][r], sv[tt][1][r]), fmaxf(sv[tt][2][r], sv[tt][3][r]));
            mx[tt][r] = redmax16(m);
            need = need || (mx[tt][r] > mrun[tt][r] + 4.0f);
          }
        }
        if (__ballot(need)) {
#pragma unroll
          for (int tt = 0; tt < 2; ++tt)
#pragma unroll
            for (int r = 0; r < 4; ++r) {
              float mnew = fmaxf(mrun[tt][r], mx[tt][r]);
              float al = fexp2(mrun[tt][r] - mnew);
              mrun[tt][r] = mnew;
              lrun[tt][r] *= al;
#pragma unroll
              for (int ns = 0; ns < 4; ++ns) acc_o[tt][ns][r] *= al;
            }
        }
#pragma unroll
        for (int tt = 0; tt < 2; ++tt) {
#pragma unroll
          for (int ns = 0; ns < 4; ++ns)
#pragma unroll
            for (int r = 0; r < 4; ++r)
              sv[tt][ns][r] = fexp2(sv[tt][ns][r] - mrun[tt][r]);
#pragma unroll
          for (int r = 0; r < 4; ++r) {
            float s2 = (sv[tt][0][r] + sv[tt][1][r]) + (sv[tt][2][r] + sv[tt][3][r]);
            lrun[tt][r] += redsum16(s2);
          }
        }

        // ---- P -> LDS (bf16, swizzled, per-wave, 32 rows) ----
        short* Pw = Pl[w];
#pragma unroll
        for (int tt = 0; tt < 2; ++tt)
#pragma unroll
          for (int ns = 0; ns < 4; ++ns)
#pragma unroll
            for (int r = 0; r < 4; ++r) {
              int row = tt * 16 + g * 4 + r;
              int byte = row * 128 + (((ns * 16 + c) * 2) ^ ((row & 7) << 4));
              *reinterpret_cast<short*>(reinterpret_cast<char*>(Pw) + byte) = f2bf(sv[tt][ns][r]);
            }

        // ---- O += P V (V-frag shared across both row-subtiles) ----
        __builtin_amdgcn_s_setprio(1);
#pragma unroll
        for (int kk = 0; kk < 2; ++kk) {
          int kbyte = (kk * 32 + g * 8) * 2;
          short8 pf[2];
#pragma unroll
          for (int tt = 0; tt < 2; ++tt) {
            int rowP = tt * 16 + c;
            int byteP = rowP * 128 + (kbyte ^ ((c & 7) << 4));
            pf[tt] = *reinterpret_cast<const short8*>(reinterpret_cast<char*>(Pw) + byteP);
          }
#pragma unroll
          for (int ns = 0; ns < 4; ++ns) {
            int rowV = ns * 16 + c;
            int byteV = rowV * 128 + (kbyte ^ ((rowV & 7) << 4));
            short8 vf = *reinterpret_cast<const short8*>((char*)Vl[sel] + byteV);
            acc_o[0][ns] = __builtin_amdgcn_mfma_f32_16x16x32_bf16(pf[0], vf, acc_o[0][ns], 0, 0, 0);
            acc_o[1][ns] = __builtin_amdgcn_mfma_f32_16x16x32_bf16(pf[1], vf, acc_o[1][ns], 0, 0, 0);
          }
        }
        __builtin_amdgcn_s_setprio(0);
      }

      __builtin_amdgcn_sched_barrier(0);
      __builtin_amdgcn_s_barrier();
    }

    // ---- epilogue ----
    if (direct) {
#pragma unroll
      for (int tt = 0; tt < 2; ++tt)
#pragma unroll
        for (int ns = 0; ns < 4; ++ns)
#pragma unroll
          for (int r = 0; r < 4; ++r) {
            int lg = l0 + w * 32 + tt * 16 + g * 4 + r;
            int d = ns * 16 + c;
            Y[((size_t)bb * LSEQ + lg) * DIM + hh * HS + d] = f2bf(acc_o[tt][ns][r] / lrun[tt][r]);
          }
    } else {
      char* pb = Part + (size_t)pslot * PART_BYTES;
      short* Op = (short*)pb;
      float* mp = (float*)(pb + 16384);
      float* lp = (float*)(pb + 16896);
#pragma unroll
      for (int tt = 0; tt < 2; ++tt)
#pragma unroll
        for (int r = 0; r < 4; ++r) {
          int row = w * 32 + tt * 16 + g * 4 + r;
#pragma unroll
          for (int ns = 0; ns < 4; ++ns)
            Op[row * 64 + ns * 16 + c] = f2bf(acc_o[tt][ns][r]);
          if (c == 0) { mp[row] = mrun[tt][r]; lp[row] = lrun[tt][r]; }
        }
    }
  };

  const int qtH = 15 - p;
  const int sp = (7 - p) * 32 + bh;
  if (half == 0) {
    process(qtH, 0, 17, false, sp * 2);
  } else {
    process(qtH, 17, 2 * qtH + 2, false, sp * 2 + 1);
    process(p, 0, 2 * p + 2, true, 0);
  }

  // ---- in-kernel flash-decode merge: second finisher of the pair merges ----
  {
    __threadfence();                       // release partial stores
    __syncthreads();
    if (t == 0) oldsh = atomicAdd(&Cnt[sp], 1u);
    __syncthreads();
    if (oldsh == 1) {
      __threadfence();                     // acquire other half's stores
      int qt = qtH;
      int row = t >> 1, seg = t & 1;       // row 0..127, seg covers 32 cols

      const char* p0 = Part + (size_t)(sp * 2) * PART_BYTES;
      const char* p1 = p0 + PART_BYTES;
      float m0 = ((const float*)(p0 + 16384))[row];
      float l0 = ((const float*)(p0 + 16896))[row];
      float m1 = ((const float*)(p1 + 16384))[row];
      float l1 = ((const float*)(p1 + 16896))[row];
      float M = fmaxf(m0, m1);
      float a0 = fexp2(m0 - M), a1 = fexp2(m1 - M);
      float inv = 1.0f / (l0 * a0 + l1 * a1);

      const short* O0 = (const short*)p0 + row * 64 + seg * 32;
      const short* O1 = (const short*)p1 + row * 64 + seg * 32;
      int lg = qt * 128 + row;
      short* dst = Y + ((size_t)bb * LSEQ + lg) * DIM + hh * HS + seg * 32;
#pragma unroll
      for (int v = 0; v < 4; ++v) {
        short8 s0v = *reinterpret_cast<const short8*>(O0 + v * 8);
        short8 s1v = *reinterpret_cast<const short8*>(O1 + v * 8);
        short out[8];
#pragma unroll
        for (int e = 0; e < 8; ++e)
          out[e] = f2bf((bf2f(s0v[e]) * a0 + bf2f(s1v[e]) * a1) * inv);
        *reinterpret_cast<short8*>(dst + v * 8) = *reinterpret_cast<short8*>(out);
      }
    }
  }
}

// ---------------- launch ----------------

extern "C" void kernel_launch(void* const* d_in, const int* in_sizes, int n_in,
                              void* d_out, int out_size, void* d_ws, size_t ws_size,
                              hipStream_t stream)
{
  const float* x     = (const float*)d_in[0];
  const float* Wqkv  = (const float*)d_in[1];
  const float* bqkv  = (const float*)d_in[2];
  const float* Wproj = (const float*)d_in[3];
  const float* bproj = (const float*)d_in[4];
  const float* Er    = (const float*)d_in[5];

  char* ws = (char*)d_ws;
  short* xb     = (short*)(ws + 0);                       // 4096x1024 bf16 (GEMM1 input)
  short* WqkvT  = (short*)(ws + 8388608);                 // 3072x1024 bf16
  short* WprojT = (short*)(ws + 14680064);                // 1024x1024 bf16
  short* Erb    = (short*)(ws + 16777216);                // 2048x64 bf16
  short* qB     = (short*)(ws + 17039360);                // [32][2048][64] bf16
  short* kB     = (short*)(ws + 25427968);
  short* vTB    = (short*)(ws + 33816576);                // [32][64][2048] bf16 (v transposed)
  short* yB     = (short*)(ws + 42205184);                // 4096x1024 bf16
  char*  Part   = ws;                                     // 512*17408 = 8912896 B, reuses
                                                          // xb+WqkvT-head (dead during attn)
  unsigned* Cnt = (unsigned*)(ws + 8912896);              // 256 counters (WqkvT region,
                                                          // dead during attn)

  prep_kernel<<<dim3(5248), 256, 0, stream>>>(x, Er, Wqkv, Wproj, xb, Erb, WqkvT, WprojT);

  gemm1_kernel<<<dim3(3072 / 128, 4096 / 128), 256, 0, stream>>>(
      xb, WqkvT, bqkv, 4096, 3072, 1024, qB, kB, vTB);

  hipMemsetAsync(Cnt, 0, 256 * sizeof(unsigned), stream);

  attn_kernel<<<dim3(512), 256, 0, stream>>>(qB, kB, vTB, Erb, yB, Part, Cnt);

  gemm2_kernel<<<dim3(1024 / 128, 4096 / 64), 256, 0, stream>>>(
      yB, WprojT, bproj, (float*)d_out);
}

// Round 14
// 242.173 us; speedup vs baseline: 1.0947x; 1.0947x over previous
//
#include <hip/hip_runtime.h>
#include <hip/hip_bf16.h>

#define LSEQ 2048
#define NH 16
#define HS 64
#define DIM 1024

typedef __attribute__((ext_vector_type(8))) short short8;
typedef __attribute__((ext_vector_type(4))) float f32x4;

typedef const __attribute__((address_space(1))) void g_void_t;
typedef __attribute__((address_space(3))) void s_void_t;

// 0.125 (1/sqrt(hs)) * log2(e): folded into Q so softmax runs in base 2.
#define QSCALE 0.18033688011112042f
#define PART_BYTES 17408   // [128][64] bf16 O-unnorm + f32 m[128] + f32 l[128]

static __device__ __forceinline__ short f2bf(float f) {
  __hip_bfloat16 h = __float2bfloat16(f);
  return __builtin_bit_cast(short, h);
}
static __device__ __forceinline__ float bf2f(short s) {
  __hip_bfloat16 h = __builtin_bit_cast(__hip_bfloat16, s);
  return __bfloat162float(h);
}

static __device__ __forceinline__ float fexp2(float x) {
#if __has_builtin(__builtin_amdgcn_exp2f)
  return __builtin_amdgcn_exp2f(x);
#else
  float r; asm("v_exp_f32 %0, %1" : "=v"(r) : "v"(x)); return r;
#endif
}

// DPP cross-lane move (VALU-only, no LDS pipe).
template<int CTRL>
static __device__ __forceinline__ float dpp_mov(float x) {
  return __builtin_bit_cast(float,
      __builtin_amdgcn_update_dpp(0, __builtin_bit_cast(int, x), CTRL, 0xF, 0xF, true));
}
// Butterfly over 16-lane group with independent masks:
// quad_perm[1,0,3,2]=0xB1, quad_perm[2,3,0,1]=0x4E, row_half_mirror=0x141, row_mirror=0x140.
static __device__ __forceinline__ float redmax16(float x) {
  x = fmaxf(x, dpp_mov<0xB1>(x));
  x = fmaxf(x, dpp_mov<0x4E>(x));
  x = fmaxf(x, dpp_mov<0x141>(x));
  x = fmaxf(x, dpp_mov<0x140>(x));
  return x;
}
static __device__ __forceinline__ float redsum16(float x) {
  x += dpp_mov<0xB1>(x);
  x += dpp_mov<0x4E>(x);
  x += dpp_mov<0x141>(x);
  x += dpp_mov<0x140>(x);
  return x;
}

// ---------------- fused prep kernel (x-cast, Er-cast, Wqkv^T, Wproj^T) ----------------

__global__ void prep_kernel(const float* __restrict__ x, const float* __restrict__ Er,
                            const float* __restrict__ Wqkv, const float* __restrict__ Wproj,
                            short* __restrict__ xb, short* __restrict__ Erb,
                            short* __restrict__ WqkvT, short* __restrict__ WprojT) {
  __shared__ float tile[64][65];
  int bid = blockIdx.x;
  if (bid < 4224) {
    const float* in; short* out; int i0;
    if (bid < 4096) { in = x;  out = xb;  i0 = bid * 256; }
    else            { in = Er; out = Erb; i0 = (bid - 4096) * 256; }
    int i = i0 + threadIdx.x;
    float4 v = reinterpret_cast<const float4*>(in)[i];
    short4 o;
    o.x = f2bf(v.x); o.y = f2bf(v.y); o.z = f2bf(v.z); o.w = f2bf(v.w);
    reinterpret_cast<short4*>(out)[i] = o;
    return;
  }
  int id = bid - 4224;
  const float* W; short* Wt; int N, tx, ty;
  if (id < 768) { W = Wqkv;  Wt = WqkvT;  N = 3072; tx = id % 48; ty = id / 48; }
  else { id -= 768; W = Wproj; Wt = WprojT; N = 1024; tx = id % 16; ty = id / 16; }
  const int K = 1024;
  int k0 = ty * 64, n0 = tx * 64;
  int t = threadIdx.x;
  int r4 = t >> 6, cc = t & 63;
  for (int i = 0; i < 16; ++i) {
    int row = i * 4 + r4;
    tile[row][cc] = W[(size_t)(k0 + row) * N + (n0 + cc)];
  }
  __syncthreads();
  for (int i = 0; i < 16; ++i) {
    int row = i * 4 + r4;
    Wt[(size_t)(n0 + row) * K + (k0 + cc)] = f2bf(tile[cc][row]);
  }
}

// ---------------- GEMM1 (A[M][K] bf16 row-major, Bt[N][K] bf16 row-major) ----------------

__global__ __launch_bounds__(256, 3) void gemm1_kernel(
    const short* __restrict__ A, const short* __restrict__ Bt,
    const float* __restrict__ bias, int M, int N, int K,
    short* __restrict__ oq, short* __restrict__ ok, short* __restrict__ ov)
{
  __shared__ short Al[128 * 32];
  __shared__ short Bl[128 * 32];
  const int m0 = blockIdx.y * 128, n0 = blockIdx.x * 128;
  const int t = threadIdx.x;
  const int lane = t & 63, wave = t >> 6;
  const int wr = wave >> 1, wc = wave & 1;
  const int g = lane >> 4, c = lane & 15;
  f32x4 acc[4][4] = {};

  for (int k0 = 0; k0 < K; k0 += 32) {
    __syncthreads();
    for (int i = 0; i < 2; ++i) {
      int ch = i * 256 + t;
      int row = ch >> 2, c8 = ch & 3;
      __builtin_amdgcn_global_load_lds(
          (g_void_t*)(A + (size_t)(m0 + row) * K + k0 + c8 * 8),
          (s_void_t*)(Al + (i * 256 + wave * 64) * 8), 16, 0, 0);
      __builtin_amdgcn_global_load_lds(
          (g_void_t*)(Bt + (size_t)(n0 + row) * K + k0 + c8 * 8),
          (s_void_t*)(Bl + (i * 256 + wave * 64) * 8), 16, 0, 0);
    }
    __syncthreads();
    short8 af[4], bf[4];
#pragma unroll
    for (int mi = 0; mi < 4; ++mi) {
      int row = wr * 64 + mi * 16 + c;
      af[mi] = *reinterpret_cast<const short8*>(Al + row * 32 + g * 8);
    }
#pragma unroll
    for (int ni = 0; ni < 4; ++ni) {
      int row = wc * 64 + ni * 16 + c;
      bf[ni] = *reinterpret_cast<const short8*>(Bl + row * 32 + g * 8);
    }
#pragma unroll
    for (int mi = 0; mi < 4; ++mi)
#pragma unroll
      for (int ni = 0; ni < 4; ++ni)
        acc[mi][ni] = __builtin_amdgcn_mfma_f32_16x16x32_bf16(af[mi], bf[ni], acc[mi][ni], 0, 0, 0);
  }

#pragma unroll
  for (int mi = 0; mi < 4; ++mi)
#pragma unroll
    for (int ni = 0; ni < 4; ++ni) {
      int n = n0 + wc * 64 + ni * 16 + c;
      float bv = bias[n];
#pragma unroll
      for (int r = 0; r < 4; ++r) {
        int m = m0 + wr * 64 + mi * 16 + g * 4 + r;
        float val = acc[mi][ni][r] + bv;
        int which = n >> 10;
        int hh2 = (n >> 6) & 15;
        int d = n & 63;
        int b = m >> 11, ll = m & 2047;
        if (which == 0) {
          oq[(((size_t)b * NH + hh2) * LSEQ + ll) * HS + d] = f2bf(val * QSCALE);
        } else if (which == 1) {
          ok[(((size_t)b * NH + hh2) * LSEQ + ll) * HS + d] = f2bf(val);
        } else {
          ov[(((size_t)b * NH + hh2) * HS + d) * LSEQ + ll] = f2bf(val);
        }
      }
    }
}

// ---------------- GEMM2: 64x128 tile -> 512 wgs (2/CU co-resident) ----------------

__global__ __launch_bounds__(256, 4) void gemm2_kernel(
    const short* __restrict__ A, const short* __restrict__ Bt,
    const float* __restrict__ bias, float* __restrict__ of)
{
  __shared__ short Al[64 * 32];
  __shared__ short Bl[128 * 32];
  const int K = 1024, N = 1024;
  const int m0 = blockIdx.y * 64, n0 = blockIdx.x * 128;
  const int t = threadIdx.x;
  const int lane = t & 63, wave = t >> 6;
  const int wm = wave & 1, wn = wave >> 1;
  const int g = lane >> 4, c = lane & 15;
  f32x4 acc[2][4] = {};

  for (int k0 = 0; k0 < K; k0 += 32) {
    __syncthreads();
    {
      int row = t >> 2, c8 = t & 3;
      __builtin_amdgcn_global_load_lds(
          (g_void_t*)(A + (size_t)(m0 + row) * K + k0 + c8 * 8),
          (s_void_t*)(Al + wave * 512), 16, 0, 0);
    }
    for (int i = 0; i < 2; ++i) {
      int ch = i * 256 + t;
      int row = ch >> 2, c8 = ch & 3;
      __builtin_amdgcn_global_load_lds(
          (g_void_t*)(Bt + (size_t)(n0 + row) * K + k0 + c8 * 8),
          (s_void_t*)(Bl + (i * 256 + wave * 64) * 8), 16, 0, 0);
    }
    __syncthreads();
    short8 af[2], bf[4];
#pragma unroll
    for (int mi = 0; mi < 2; ++mi) {
      int row = wm * 32 + mi * 16 + c;
      af[mi] = *reinterpret_cast<const short8*>(Al + row * 32 + g * 8);
    }
#pragma unroll
    for (int ni = 0; ni < 4; ++ni) {
      int row = wn * 64 + ni * 16 + c;
      bf[ni] = *reinterpret_cast<const short8*>(Bl + row * 32 + g * 8);
    }
#pragma unroll
    for (int mi = 0; mi < 2; ++mi)
#pragma unroll
      for (int ni = 0; ni < 4; ++ni)
        acc[mi][ni] = __builtin_amdgcn_mfma_f32_16x16x32_bf16(af[mi], bf[ni], acc[mi][ni], 0, 0, 0);
  }

#pragma unroll
  for (int mi = 0; mi < 2; ++mi)
#pragma unroll
    for (int ni = 0; ni < 4; ++ni) {
      int n = n0 + wn * 64 + ni * 16 + c;
      float bv = bias[n];
#pragma unroll
      for (int r = 0; r < 4; ++r) {
        int m = m0 + wm * 32 + mi * 16 + g * 4 + r;
        of[(size_t)m * N + n] = acc[mi][ni][r] + bv;
      }
    }
}

// ---------------- fused flash attention with relative-position band ----------------
// R11-proven compute (77.6us) + in-kernel flash-decode merge. CRITICAL: the merge
// broadcast flag reuses Pl[0] (dead after the step loop) — NO extra __shared__,
// LDS stays exactly 81920 B so 2 wgs/CU fit (R13's 4-byte oldsh pushed LDS to
// 82432 -> 1 wg/CU -> 206us; that regression was pure LDS-boundary).

__global__ __launch_bounds__(256, 2) void attn_kernel(
    const short* __restrict__ Qb, const short* __restrict__ Kb,
    const short* __restrict__ VTb, const short* __restrict__ Erb,
    short* __restrict__ Y, char* __restrict__ Part, unsigned* __restrict__ Cnt)
{
  const int bid = blockIdx.x;
  const int jid = bid >> 5;        // 0..15
  const int bh = bid & 31;
  const int p = jid >> 1;          // 0..7
  const int half = jid & 1;
  const int bb = bh >> 4, hh = bh & 15;
  const int t = threadIdx.x;
  const int lane = t & 63, w = t >> 6;   // wave 0..3
  const int g = lane >> 4, c = lane & 15;
  const int r8 = lane >> 3;
  const int c16b = (lane & 7) * 16;

  __shared__ short Kl[2][64 * 64];       // 16 KB dbuf
  __shared__ short Vl[2][64 * 64];       // 16 KB dbuf (V^T rows = d)
  __shared__ short El[4][64 * 64];       // 32 KB circular, slot = chunk & 3
  __shared__ short Pl[4][32 * 64];       // 16 KB per-wave P (32 rows); Pl[0][0..1]
                                         // doubles as the merge flag after the loop

  auto stage_KV = [&](int step, int sel) {
#pragma unroll
    for (int jj = 0; jj < 2; ++jj) {
      int rr = w * 16 + jj * 8 + r8;
      const char* Kg = (const char*)(Kb + ((size_t)bh * LSEQ + step * 64) * HS);
      __builtin_amdgcn_global_load_lds(
          (g_void_t*)(Kg + rr * 128 + (c16b ^ ((rr & 7) << 4))),
          (s_void_t*)(&Kl[sel][(w * 16 + jj * 8) * 64]), 16, 0, 0);
    }
#pragma unroll
    for (int jj = 0; jj < 2; ++jj) {
      int rr = w * 16 + jj * 8 + r8;     // d index
      const char* Vg = (const char*)(VTb + ((size_t)bh * HS + rr) * LSEQ + step * 64);
      __builtin_amdgcn_global_load_lds(
          (g_void_t*)(Vg + (c16b ^ ((rr & 7) << 4))),
          (s_void_t*)(&Vl[sel][(w * 16 + jj * 8) * 64]), 16, 0, 0);
    }
  };
  auto stage_E = [&](int chunk) {
    int slot = chunk & 3;
#pragma unroll
    for (int jj = 0; jj < 2; ++jj) {
      int rr = w * 16 + jj * 8 + r8;     // local row 0..63
      int e = chunk * 64 + rr;
      if (e > LSEQ - 1) e = LSEQ - 1;    // clamped rows feed masked cols only
      if (e < 0) e = 0;
      __builtin_amdgcn_global_load_lds(
          (g_void_t*)((const char*)Erb + (size_t)e * 128 + (c16b ^ ((rr & 7) << 4))),
          (s_void_t*)(&El[slot][(w * 16 + jj * 8) * 64]), 16, 0, 0);
    }
  };

  // process one 128-row q-tile's k-steps [s0, s1)
  auto process = [&](int qt, int s0, int s1, bool direct, int pslot) {
    const int l0 = qt * 128;
    const int c00 = 31 - 2 * qt;         // R7-verified Er chunk base
    const int nsteps = 2 * qt + 2;

    short8 qf[2][2];
#pragma unroll
    for (int tt = 0; tt < 2; ++tt)
#pragma unroll
      for (int kk = 0; kk < 2; ++kk)
        qf[tt][kk] = *reinterpret_cast<const short8*>(
            Qb + ((size_t)bh * LSEQ + l0 + w * 32 + tt * 16 + c) * HS + kk * 32 + g * 8);

    stage_KV(s0, s0 & 1);
    stage_E(c00 + s0 - 1); stage_E(c00 + s0); stage_E(c00 + s0 + 1);

    f32x4 acc_o[2][4] = {};
    float mrun[2][4], lrun[2][4];
#pragma unroll
    for (int tt = 0; tt < 2; ++tt)
#pragma unroll
      for (int r = 0; r < 4; ++r) { mrun[tt][r] = -1e30f; lrun[tt][r] = 0.0f; }

    for (int s = s0; s < s1; ++s) {
      const int sel = s & 1;
      const int c0 = c00 + s;

      if (s + 1 < s1) {
        stage_KV(s + 1, sel ^ 1);        // safe: bottom barrier of s-1 passed
        stage_E(c0 + 2);                 // slot (c0+2)&3 == (c0-2)&3, free
        asm volatile("s_waitcnt vmcnt(6)" ::: "memory");
      } else {
        asm volatile("s_waitcnt vmcnt(0)" ::: "memory");
      }
      __builtin_amdgcn_s_barrier();
      __builtin_amdgcn_sched_barrier(0);

      // last step of the tile: waves 0,1 (rows < 64) fully causally masked
      const bool deadwave = (s == nsteps - 1) && (w < 2);
      if (!deadwave) {
        const bool maskstep = (s >= 2 * qt);

        __builtin_amdgcn_s_setprio(1);
        // ---- G = Q · ErBand^T: 6 shared windows, 10 output tiles ----
        f32x4 ga[2][5];
#pragma unroll
        for (int tt = 0; tt < 2; ++tt)
#pragma unroll
          for (int s5 = 0; s5 < 5; ++s5) ga[tt][s5] = (f32x4){0.0f, 0.0f, 0.0f, 0.0f};
#pragma unroll
        for (int u = 0; u < 6; ++u) {
          int rb = ((2 - 2 * w) + u) * 16 + c;   // signed band row -64..126
          int chunk = c0 + (rb >> 6);            // arithmetic shift
          int phys = ((chunk & 3) << 6) | (rb & 63);
#pragma unroll
          for (int kk = 0; kk < 2; ++kk) {
            int byte = phys * 128 + (((kk * 32 + g * 8) * 2) ^ ((rb & 7) << 4));
            short8 ef = *reinterpret_cast<const short8*>((char*)El + byte);
            if (u >= 1) ga[0][u - 1] = __builtin_amdgcn_mfma_f32_16x16x32_bf16(qf[0][kk], ef, ga[0][u - 1], 0, 0, 0);
            if (u <= 4) ga[1][u]     = __builtin_amdgcn_mfma_f32_16x16x32_bf16(qf[1][kk], ef, ga[1][u], 0, 0, 0);
          }
        }

        // ---- S = Q K^T (K-frag shared across both row-subtiles) ----
        f32x4 sa[2][4];
#pragma unroll
        for (int tt = 0; tt < 2; ++tt)
#pragma unroll
          for (int ns = 0; ns < 4; ++ns) sa[tt][ns] = (f32x4){0.0f, 0.0f, 0.0f, 0.0f};
#pragma unroll
        for (int ns = 0; ns < 4; ++ns) {
#pragma unroll
          for (int kk = 0; kk < 2; ++kk) {
            int row = ns * 16 + c;
            int byte = row * 128 + (((kk * 32 + g * 8) * 2) ^ ((row & 7) << 4));
            short8 kf = *reinterpret_cast<const short8*>((char*)Kl[sel] + byte);
            sa[0][ns] = __builtin_amdgcn_mfma_f32_16x16x32_bf16(qf[0][kk], kf, sa[0][ns], 0, 0, 0);
            sa[1][ns] = __builtin_amdgcn_mfma_f32_16x16x32_bf16(qf[1][kk], kf, sa[1][ns], 0, 0, 0);
          }
        }
        __builtin_amdgcn_s_setprio(0);

        // ---- skew + mask + online softmax per row-subtile ----
        float sv[2][4][4];
        bool need = false;
        float mx[2][4];
#pragma unroll
        for (int tt = 0; tt < 2; ++tt) {
#pragma unroll
          for (int r = 0; r < 4; ++r) {
            int i4 = g * 4 + r;
            int u0 = c + 15 - i4;            // 0..30
            int srcl = (g << 4) | (u0 & 15);
            float bp[5];
#pragma unroll
            for (int s5 = 0; s5 < 5; ++s5) bp[s5] = __shfl(ga[tt][s5][r], srcl, 64);
            bool lo = (u0 < 16);
            int thr = (l0 - 64 * s) + w * 32 + tt * 16 + i4;
#pragma unroll
            for (int ns = 0; ns < 4; ++ns) {
              float srel = lo ? bp[ns] : bp[ns + 1];
              float xx = sa[tt][ns][r] + srel;
              if (maskstep && (ns * 16 + c > thr)) xx = -1e30f;
              sv[tt][ns][r] = xx;
            }
          }
#pragma unroll
          for (int r = 0; r < 4; ++r) {
            float m = fmaxf(fmaxf(sv[tt][0][r], sv[tt][1][r]), fmaxf(sv[tt][2][r], sv[tt][3][r]));
            mx[tt][r] = redmax16(m);
            need = need || (mx[tt][r] > mrun[tt][r] + 4.0f);
          }
        }
        if (__ballot(need)) {
#pragma unroll
          for (int tt = 0; tt < 2; ++tt)
#pragma unroll
            for (int r = 0; r < 4; ++r) {
              float mnew = fmaxf(mrun[tt][r], mx[tt][r]);
              float al = fexp2(mrun[tt][r] - mnew);
              mrun[tt][r] = mnew;
              lrun[tt][r] *= al;
#pragma unroll
              for (int ns = 0; ns < 4; ++ns) acc_o[tt][ns][r] *= al;
            }
        }
#pragma unroll
        for (int tt = 0; tt < 2; ++tt) {
#pragma unroll
          for (int ns = 0; ns < 4; ++ns)
#pragma unroll
            for (int r = 0; r < 4; ++r)
              sv[tt][ns][r] = fexp2(sv[tt][ns][r] - mrun[tt][r]);
#pragma unroll
          for (int r = 0; r < 4; ++r) {
            float s2 = (sv[tt][0][r] + sv[tt][1][r]) + (sv[tt][2][r] + sv[tt][3][r]);
            lrun[tt][r] += redsum16(s2);
          }
        }

        // ---- P -> LDS (bf16, swizzled, per-wave, 32 rows) ----
        short* Pw = Pl[w];
#pragma unroll
        for (int tt = 0; tt < 2; ++tt)
#pragma unroll
          for (int ns = 0; ns < 4; ++ns)
#pragma unroll
            for (int r = 0; r < 4; ++r) {
              int row = tt * 16 + g * 4 + r;
              int byte = row * 128 + (((ns * 16 + c) * 2) ^ ((row & 7) << 4));
              *reinterpret_cast<short*>(reinterpret_cast<char*>(Pw) + byte) = f2bf(sv[tt][ns][r]);
            }

        // ---- O += P V (V-frag shared across both row-subtiles) ----
        __builtin_amdgcn_s_setprio(1);
#pragma unroll
        for (int kk = 0; kk < 2; ++kk) {
          int kbyte = (kk * 32 + g * 8) * 2;
          short8 pf[2];
#pragma unroll
          for (int tt = 0; tt < 2; ++tt) {
            int rowP = tt * 16 + c;
            int byteP = rowP * 128 + (kbyte ^ ((c & 7) << 4));
            pf[tt] = *reinterpret_cast<const short8*>(reinterpret_cast<char*>(Pw) + byteP);
          }
#pragma unroll
          for (int ns = 0; ns < 4; ++ns) {
            int rowV = ns * 16 + c;
            int byteV = rowV * 128 + (kbyte ^ ((rowV & 7) << 4));
            short8 vf = *reinterpret_cast<const short8*>((char*)Vl[sel] + byteV);
            acc_o[0][ns] = __builtin_amdgcn_mfma_f32_16x16x32_bf16(pf[0], vf, acc_o[0][ns], 0, 0, 0);
            acc_o[1][ns] = __builtin_amdgcn_mfma_f32_16x16x32_bf16(pf[1], vf, acc_o[1][ns], 0, 0, 0);
          }
        }
        __builtin_amdgcn_s_setprio(0);
      }

      __builtin_amdgcn_sched_barrier(0);
      __builtin_amdgcn_s_barrier();
    }

    // ---- epilogue ----
    if (direct) {
#pragma unroll
      for (int tt = 0; tt < 2; ++tt)
#pragma unroll
        for (int ns = 0; ns < 4; ++ns)
#pragma unroll
          for (int r = 0; r < 4; ++r) {
            int lg = l0 + w * 32 + tt * 16 + g * 4 + r;
            int d = ns * 16 + c;
            Y[((size_t)bb * LSEQ + lg) * DIM + hh * HS + d] = f2bf(acc_o[tt][ns][r] / lrun[tt][r]);
          }
    } else {
      char* pb = Part + (size_t)pslot * PART_BYTES;
      short* Op = (short*)pb;
      float* mp = (float*)(pb + 16384);
      float* lp = (float*)(pb + 16896);
#pragma unroll
      for (int tt = 0; tt < 2; ++tt)
#pragma unroll
        for (int r = 0; r < 4; ++r) {
          int row = w * 32 + tt * 16 + g * 4 + r;
#pragma unroll
          for (int ns = 0; ns < 4; ++ns)
            Op[row * 64 + ns * 16 + c] = f2bf(acc_o[tt][ns][r]);
          if (c == 0) { mp[row] = mrun[tt][r]; lp[row] = lrun[tt][r]; }
        }
    }
  };

  const int qtH = 15 - p;
  const int sp = (7 - p) * 32 + bh;
  if (half == 0) {
    process(qtH, 0, 17, false, sp * 2);
  } else {
    process(qtH, 17, 2 * qtH + 2, false, sp * 2 + 1);
    process(p, 0, 2 * p + 2, true, 0);
  }

  // ---- in-kernel flash-decode merge: second finisher of the pair merges ----
  // Broadcast flag reuses Pl[0] (dead after the step loops) — zero extra LDS.
  {
    volatile unsigned* flag = (volatile unsigned*)&Pl[0][0];
    __threadfence();                       // release partial stores
    __syncthreads();
    if (t == 0) *flag = atomicAdd(&Cnt[sp], 1u);
    __syncthreads();
    unsigned oldv = *flag;
    if (oldv == 1) {
      __threadfence();                     // acquire other half's stores
      int qt = qtH;
      int row = t >> 1, seg = t & 1;       // row 0..127, seg covers 32 cols

      const char* p0 = Part + (size_t)(sp * 2) * PART_BYTES;
      const char* p1 = p0 + PART_BYTES;
      float m0 = ((const float*)(p0 + 16384))[row];
      float l0 = ((const float*)(p0 + 16896))[row];
      float m1 = ((const float*)(p1 + 16384))[row];
      float l1 = ((const float*)(p1 + 16896))[row];
      float M = fmaxf(m0, m1);
      float a0 = fexp2(m0 - M), a1 = fexp2(m1 - M);
      float inv = 1.0f / (l0 * a0 + l1 * a1);

      const short* O0 = (const short*)p0 + row * 64 + seg * 32;
      const short* O1 = (const short*)p1 + row * 64 + seg * 32;
      int lg = qt * 128 + row;
      short* dst = Y + ((size_t)bb * LSEQ + lg) * DIM + hh * HS + seg * 32;
#pragma unroll
      for (int v = 0; v < 4; ++v) {
        short8 s0v = *reinterpret_cast<const short8*>(O0 + v * 8);
        short8 s1v = *reinterpret_cast<const short8*>(O1 + v * 8);
        short out[8];
#pragma unroll
        for (int e = 0; e < 8; ++e)
          out[e] = f2bf((bf2f(s0v[e]) * a0 + bf2f(s1v[e]) * a1) * inv);
        *reinterpret_cast<short8*>(dst + v * 8) = *reinterpret_cast<short8*>(out);
      }
    }
  }
}

// ---------------- launch ----------------

extern "C" void kernel_launch(void* const* d_in, const int* in_sizes, int n_in,
                              void* d_out, int out_size, void* d_ws, size_t ws_size,
                              hipStream_t stream)
{
  const float* x     = (const float*)d_in[0];
  const float* Wqkv  = (const float*)d_in[1];
  const float* bqkv  = (const float*)d_in[2];
  const float* Wproj = (const float*)d_in[3];
  const float* bproj = (const float*)d_in[4];
  const float* Er    = (const float*)d_in[5];

  char* ws = (char*)d_ws;
  short* xb     = (short*)(ws + 0);                       // 4096x1024 bf16 (GEMM1 input)
  short* WqkvT  = (short*)(ws + 8388608);                 // 3072x1024 bf16
  short* WprojT = (short*)(ws + 14680064);                // 1024x1024 bf16
  short* Erb    = (short*)(ws + 16777216);                // 2048x64 bf16
  short* qB     = (short*)(ws + 17039360);                // [32][2048][64] bf16
  short* kB     = (short*)(ws + 25427968);
  short* vTB    = (short*)(ws + 33816576);                // [32][64][2048] bf16 (v transposed)
  short* yB     = (short*)(ws + 42205184);                // 4096x1024 bf16
  char*  Part   = ws;                                     // 512*17408 = 8912896 B, reuses
                                                          // xb+WqkvT-head (dead during attn)
  unsigned* Cnt = (unsigned*)(ws + 8912896);              // 256 counters (WqkvT region,
                                                          // dead during attn)

  prep_kernel<<<dim3(5248), 256, 0, stream>>>(x, Er, Wqkv, Wproj, xb, Erb, WqkvT, WprojT);

  gemm1_kernel<<<dim3(3072 / 128, 4096 / 128), 256, 0, stream>>>(
      xb, WqkvT, bqkv, 4096, 3072, 1024, qB, kB, vTB);

  hipMemsetAsync(Cnt, 0, 256 * sizeof(unsigned), stream);

  attn_kernel<<<dim3(512), 256, 0, stream>>>(qB, kB, vTB, Erb, yB, Part, Cnt);

  gemm2_kernel<<<dim3(1024 / 128, 4096 / 64), 256, 0, stream>>>(
      yB, WprojT, bproj, (float*)d_out);
}

// Round 15
// 142.991 us; speedup vs baseline: 1.8540x; 1.6936x over previous
//
#include <hip/hip_runtime.h>
#include <hip/hip_bf16.h>

#define LSEQ 2048
#define NH 16
#define HS 64
#define DIM 1024

typedef __attribute__((ext_vector_type(8))) short short8;
typedef __attribute__((ext_vector_type(4))) float f32x4;

typedef const __attribute__((address_space(1))) void g_void_t;
typedef __attribute__((address_space(3))) void s_void_t;

// 0.125 (1/sqrt(hs)) * log2(e): folded into Q so softmax runs in base 2.
#define QSCALE 0.18033688011112042f

static __device__ __forceinline__ short f2bf(float f) {
  __hip_bfloat16 h = __float2bfloat16(f);
  return __builtin_bit_cast(short, h);
}

static __device__ __forceinline__ float fexp2(float x) {
#if __has_builtin(__builtin_amdgcn_exp2f)
  return __builtin_amdgcn_exp2f(x);
#else
  float r; asm("v_exp_f32 %0, %1" : "=v"(r) : "v"(x)); return r;
#endif
}

// DPP cross-lane move (VALU-only, no LDS pipe).
template<int CTRL>
static __device__ __forceinline__ float dpp_mov(float x) {
  return __builtin_bit_cast(float,
      __builtin_amdgcn_update_dpp(0, __builtin_bit_cast(int, x), CTRL, 0xF, 0xF, true));
}
// Butterfly over 16-lane group with independent masks:
// quad_perm[1,0,3,2]=0xB1, quad_perm[2,3,0,1]=0x4E, row_half_mirror=0x141, row_mirror=0x140.
static __device__ __forceinline__ float redmax16(float x) {
  x = fmaxf(x, dpp_mov<0xB1>(x));
  x = fmaxf(x, dpp_mov<0x4E>(x));
  x = fmaxf(x, dpp_mov<0x141>(x));
  x = fmaxf(x, dpp_mov<0x140>(x));
  return x;
}
static __device__ __forceinline__ float redsum16(float x) {
  x += dpp_mov<0xB1>(x);
  x += dpp_mov<0x4E>(x);
  x += dpp_mov<0x141>(x);
  x += dpp_mov<0x140>(x);
  return x;
}

// ---------------- fused prep kernel (x-cast, Er-cast, Wqkv^T, Wproj^T) ----------------

__global__ void prep_kernel(const float* __restrict__ x, const float* __restrict__ Er,
                            const float* __restrict__ Wqkv, const float* __restrict__ Wproj,
                            short* __restrict__ xb, short* __restrict__ Erb,
                            short* __restrict__ WqkvT, short* __restrict__ WprojT) {
  __shared__ float tile[64][65];
  int bid = blockIdx.x;
  if (bid < 4224) {
    const float* in; short* out; int i0;
    if (bid < 4096) { in = x;  out = xb;  i0 = bid * 256; }
    else            { in = Er; out = Erb; i0 = (bid - 4096) * 256; }
    int i = i0 + threadIdx.x;
    float4 v = reinterpret_cast<const float4*>(in)[i];
    short4 o;
    o.x = f2bf(v.x); o.y = f2bf(v.y); o.z = f2bf(v.z); o.w = f2bf(v.w);
    reinterpret_cast<short4*>(out)[i] = o;
    return;
  }
  int id = bid - 4224;
  const float* W; short* Wt; int N, tx, ty;
  if (id < 768) { W = Wqkv;  Wt = WqkvT;  N = 3072; tx = id % 48; ty = id / 48; }
  else { id -= 768; W = Wproj; Wt = WprojT; N = 1024; tx = id % 16; ty = id / 16; }
  const int K = 1024;
  int k0 = ty * 64, n0 = tx * 64;
  int t = threadIdx.x;
  int r4 = t >> 6, cc = t & 63;
  for (int i = 0; i < 16; ++i) {
    int row = i * 4 + r4;
    tile[row][cc] = W[(size_t)(k0 + row) * N + (n0 + cc)];
  }
  __syncthreads();
  for (int i = 0; i < 16; ++i) {
    int row = i * 4 + r4;
    Wt[(size_t)(n0 + row) * K + (k0 + cc)] = f2bf(tile[cc][row]);
  }
}

// ---------------- GEMM1 (A[M][K] bf16 row-major, Bt[N][K] bf16 row-major) ----------------
// Scatter q/k row-major (q pre-scaled by QSCALE), v TRANSPOSED [bh][d][l].
// launch_bounds(256,3): 768 wgs want 3/CU resident.

__global__ __launch_bounds__(256, 3) void gemm1_kernel(
    const short* __restrict__ A, const short* __restrict__ Bt,
    const float* __restrict__ bias, int M, int N, int K,
    short* __restrict__ oq, short* __restrict__ ok, short* __restrict__ ov)
{
  __shared__ short Al[128 * 32];
  __shared__ short Bl[128 * 32];
  const int m0 = blockIdx.y * 128, n0 = blockIdx.x * 128;
  const int t = threadIdx.x;
  const int lane = t & 63, wave = t >> 6;
  const int wr = wave >> 1, wc = wave & 1;
  const int g = lane >> 4, c = lane & 15;
  f32x4 acc[4][4] = {};

  for (int k0 = 0; k0 < K; k0 += 32) {
    __syncthreads();
    for (int i = 0; i < 2; ++i) {
      int ch = i * 256 + t;
      int row = ch >> 2, c8 = ch & 3;
      __builtin_amdgcn_global_load_lds(
          (g_void_t*)(A + (size_t)(m0 + row) * K + k0 + c8 * 8),
          (s_void_t*)(Al + (i * 256 + wave * 64) * 8), 16, 0, 0);
      __builtin_amdgcn_global_load_lds(
          (g_void_t*)(Bt + (size_t)(n0 + row) * K + k0 + c8 * 8),
          (s_void_t*)(Bl + (i * 256 + wave * 64) * 8), 16, 0, 0);
    }
    __syncthreads();
    short8 af[4], bf[4];
#pragma unroll
    for (int mi = 0; mi < 4; ++mi) {
      int row = wr * 64 + mi * 16 + c;
      af[mi] = *reinterpret_cast<const short8*>(Al + row * 32 + g * 8);
    }
#pragma unroll
    for (int ni = 0; ni < 4; ++ni) {
      int row = wc * 64 + ni * 16 + c;
      bf[ni] = *reinterpret_cast<const short8*>(Bl + row * 32 + g * 8);
    }
#pragma unroll
    for (int mi = 0; mi < 4; ++mi)
#pragma unroll
      for (int ni = 0; ni < 4; ++ni)
        acc[mi][ni] = __builtin_amdgcn_mfma_f32_16x16x32_bf16(af[mi], bf[ni], acc[mi][ni], 0, 0, 0);
  }

#pragma unroll
  for (int mi = 0; mi < 4; ++mi)
#pragma unroll
    for (int ni = 0; ni < 4; ++ni) {
      int n = n0 + wc * 64 + ni * 16 + c;
      float bv = bias[n];
#pragma unroll
      for (int r = 0; r < 4; ++r) {
        int m = m0 + wr * 64 + mi * 16 + g * 4 + r;
        float val = acc[mi][ni][r] + bv;
        int which = n >> 10;
        int hh2 = (n >> 6) & 15;
        int d = n & 63;
        int b = m >> 11, ll = m & 2047;
        if (which == 0) {
          oq[(((size_t)b * NH + hh2) * LSEQ + ll) * HS + d] = f2bf(val * QSCALE);
        } else if (which == 1) {
          ok[(((size_t)b * NH + hh2) * LSEQ + ll) * HS + d] = f2bf(val);
        } else {
          // transposed: vT[bh][d][l]; consecutive r -> consecutive l (coalesced)
          ov[(((size_t)b * NH + hh2) * HS + d) * LSEQ + ll] = f2bf(val);
        }
      }
    }
}

// ---------------- GEMM2: 64x128 tile -> 512 wgs (2/CU co-resident) ----------------
// A [4096][1024] bf16, Bt [1024][1024] bf16, out f32 + bias. Old 128x128 tiling gave
// only 256 wgs = 1 wg/CU: every vmcnt(0)+barrier drain fully exposed. 2/CU hides it.

__global__ __launch_bounds__(256, 4) void gemm2_kernel(
    const short* __restrict__ A, const short* __restrict__ Bt,
    const float* __restrict__ bias, float* __restrict__ of)
{
  __shared__ short Al[64 * 32];       // 4 KB
  __shared__ short Bl[128 * 32];      // 8 KB
  const int K = 1024, N = 1024;
  const int m0 = blockIdx.y * 64, n0 = blockIdx.x * 128;
  const int t = threadIdx.x;
  const int lane = t & 63, wave = t >> 6;
  const int wm = wave & 1, wn = wave >> 1;   // wave covers 32(M) x 64(N)
  const int g = lane >> 4, c = lane & 15;
  f32x4 acc[2][4] = {};

  for (int k0 = 0; k0 < K; k0 += 32) {
    __syncthreads();
    {
      int row = t >> 2, c8 = t & 3;          // 64 rows x 4 chunks
      __builtin_amdgcn_global_load_lds(
          (g_void_t*)(A + (size_t)(m0 + row) * K + k0 + c8 * 8),
          (s_void_t*)(Al + wave * 512), 16, 0, 0);
    }
    for (int i = 0; i < 2; ++i) {
      int ch = i * 256 + t;
      int row = ch >> 2, c8 = ch & 3;
      __builtin_amdgcn_global_load_lds(
          (g_void_t*)(Bt + (size_t)(n0 + row) * K + k0 + c8 * 8),
          (s_void_t*)(Bl + (i * 256 + wave * 64) * 8), 16, 0, 0);
    }
    __syncthreads();
    short8 af[2], bf[4];
#pragma unroll
    for (int mi = 0; mi < 2; ++mi) {
      int row = wm * 32 + mi * 16 + c;
      af[mi] = *reinterpret_cast<const short8*>(Al + row * 32 + g * 8);
    }
#pragma unroll
    for (int ni = 0; ni < 4; ++ni) {
      int row = wn * 64 + ni * 16 + c;
      bf[ni] = *reinterpret_cast<const short8*>(Bl + row * 32 + g * 8);
    }
#pragma unroll
    for (int mi = 0; mi < 2; ++mi)
#pragma unroll
      for (int ni = 0; ni < 4; ++ni)
        acc[mi][ni] = __builtin_amdgcn_mfma_f32_16x16x32_bf16(af[mi], bf[ni], acc[mi][ni], 0, 0, 0);
  }

#pragma unroll
  for (int mi = 0; mi < 2; ++mi)
#pragma unroll
    for (int ni = 0; ni < 4; ++ni) {
      int n = n0 + wn * 64 + ni * 16 + c;
      float bv = bias[n];
#pragma unroll
      for (int r = 0; r < 4; ++r) {
        int m = m0 + wm * 32 + mi * 16 + g * 4 + r;
        of[(size_t)m * N + n] = acc[mi][ni][r] + bv;
      }
    }
}

// ---------------- fused flash attention with relative-position band ----------------
// R5-proven structure (82 us): grid 512, wg = (pair p, bh) processes q-tiles 31-p
// then p -> 33 uniform steps, 2 wg/CU overlapped. K/V^T dbuf, Er 4-slot circular,
// global_load_lds w/ pre-swizzled source, vmcnt(6), 2 barriers/step, DPP softmax,
// base-2 exp, defer-rescale, setprio on MFMA clusters.

__global__ __launch_bounds__(256, 2) void attn_kernel(
    const short* __restrict__ Qb, const short* __restrict__ Kb,
    const short* __restrict__ VTb, const short* __restrict__ Erb,
    short* __restrict__ Y)
{
  const int bid = blockIdx.x;
  const int pair = bid >> 5;
  const int bh = bid & 31;
  const int bb = bh >> 4, hh = bh & 15;
  const int t = threadIdx.x;
  const int lane = t & 63, wave = t >> 6;
  const int g = lane >> 4, c = lane & 15;
  const int r8 = lane >> 3;
  const int c16b = (lane & 7) * 16;

  __shared__ short Ql[64 * 64];            // 8 KB, row-XOR swizzled
  __shared__ short Kl[2][64 * 64];         // 16 KB
  __shared__ short Vl[2][64 * 64];         // 16 KB (V^T rows = d)
  __shared__ short El[4][64 * 64];         // 32 KB, circular, slot = chunk & 3
  __shared__ short Pl[4][16 * 64];         // 8 KB per-wave P

  auto process = [&](int qt) {
    const int l0 = qt * 64;
    const int base = 31 - qt;              // Er chunk window at step s: {base+s, base+s+1}

    // ---- stage Q ----
    const short* Qg = Qb + ((size_t)bh * LSEQ + l0) * HS;
    for (int i = 0; i < 2; ++i) {
      int ch = i * 256 + t;
      int row = ch >> 3, c8 = ch & 7;
      uint4 v = *reinterpret_cast<const uint4*>(Qg + row * HS + c8 * 8);
      int byte = row * 128 + ((c8 * 16) ^ ((row & 7) << 4));
      *reinterpret_cast<uint4*>(reinterpret_cast<char*>(Ql) + byte) = v;
    }
    __syncthreads();

    short8 qf[2];
#pragma unroll
    for (int kk = 0; kk < 2; ++kk) {
      int row = wave * 16 + c;
      int byte = row * 128 + ((kk * 32 + g * 8) * 2 ^ ((row & 7) << 4));
      qf[kk] = *reinterpret_cast<const short8*>(reinterpret_cast<char*>(Ql) + byte);
    }

    f32x4 acc_o[4] = {};
    float mrun[4], lrun[4];
#pragma unroll
    for (int r = 0; r < 4; ++r) { mrun[r] = -1e30f; lrun[r] = 0.0f; }

    auto stage_KV = [&](int step, int sel) {
      const char* Kg = (const char*)(Kb + ((size_t)bh * LSEQ + step * 64) * HS);
#pragma unroll
      for (int j = 0; j < 2; ++j) {
        int row = wave * 16 + j * 8 + r8;
        __builtin_amdgcn_global_load_lds(
            (g_void_t*)(Kg + row * 128 + (c16b ^ ((row & 7) << 4))),
            (s_void_t*)(&Kl[sel][(wave * 16 + j * 8) * 64]), 16, 0, 0);
      }
#pragma unroll
      for (int j = 0; j < 2; ++j) {
        int row = wave * 16 + j * 8 + r8;  // d index
        const char* Vg = (const char*)(VTb + ((size_t)bh * HS + row) * LSEQ + step * 64);
        __builtin_amdgcn_global_load_lds(
            (g_void_t*)(Vg + (c16b ^ ((row & 7) << 4))),
            (s_void_t*)(&Vl[sel][(wave * 16 + j * 8) * 64]), 16, 0, 0);
      }
    };
    auto stage_E = [&](int chunk) {
      int slot = chunk & 3;
#pragma unroll
      for (int j = 0; j < 2; ++j) {
        int row = wave * 16 + j * 8 + r8;          // local row 0..63
        int e = chunk * 64 + row;
        if (e > LSEQ - 1) e = LSEQ - 1;            // clamped rows feed masked cols only
        __builtin_amdgcn_global_load_lds(
            (g_void_t*)((const char*)Erb + (size_t)e * 128 + (c16b ^ ((row & 7) << 4))),
            (s_void_t*)(&El[slot][(wave * 16 + j * 8) * 64]), 16, 0, 0);
      }
    };

    // prologue: K/V for step 0, Er chunks {base, base+1}
    stage_KV(0, 0);
    stage_E(base);
    stage_E(base + 1);

    for (int s = 0; s <= qt; ++s) {
      const int sel = s & 1;
      const bool diag = (s == qt);

      if (s < qt) {
        stage_KV(s + 1, sel ^ 1);          // safe: bottom barrier of s-1 passed
        stage_E(base + s + 2);
        asm volatile("s_waitcnt vmcnt(6)" ::: "memory");
      } else {
        asm volatile("s_waitcnt vmcnt(0)" ::: "memory");
      }
      __builtin_amdgcn_s_barrier();
      __builtin_amdgcn_sched_barrier(0);

      __builtin_amdgcn_s_setprio(1);
      // ---- G = Q · ErBand^T (5 window subtiles; band row rb in circular buffer) ----
      f32x4 ga[5];
#pragma unroll
      for (int s5 = 0; s5 < 5; ++s5) {
        int rb = ((3 - wave) + s5) * 16 + c;       // 0..127
        int phys = (((base + s + (rb >> 6)) & 3) << 6) | (rb & 63);
        ga[s5] = (f32x4){0.0f, 0.0f, 0.0f, 0.0f};
#pragma unroll
        for (int kk = 0; kk < 2; ++kk) {
          int byte = phys * 128 + (((kk * 32 + g * 8) * 2) ^ ((rb & 7) << 4));
          short8 ef = *reinterpret_cast<const short8*>((char*)El + byte);
          ga[s5] = __builtin_amdgcn_mfma_f32_16x16x32_bf16(qf[kk], ef, ga[s5], 0, 0, 0);
        }
      }

      // ---- S = Q K^T ----
      f32x4 sa[4];
#pragma unroll
      for (int ns = 0; ns < 4; ++ns) {
        sa[ns] = (f32x4){0.0f, 0.0f, 0.0f, 0.0f};
#pragma unroll
        for (int kk = 0; kk < 2; ++kk) {
          int row = ns * 16 + c;
          int byte = row * 128 + (((kk * 32 + g * 8) * 2) ^ ((row & 7) << 4));
          short8 kf = *reinterpret_cast<const short8*>((char*)Kl[sel] + byte);
          sa[ns] = __builtin_amdgcn_mfma_f32_16x16x32_bf16(qf[kk], kf, sa[ns], 0, 0, 0);
        }
      }
      __builtin_amdgcn_s_setprio(0);

      // ---- skew + mask ----
      float sv[4][4];
#pragma unroll
      for (int r = 0; r < 4; ++r) {
        int i4 = g * 4 + r;
        int u0 = c + 15 - i4;                // 0..30
        int srcl = (g << 4) | (u0 & 15);
        float bp[5];
#pragma unroll
        for (int s5 = 0; s5 < 5; ++s5) bp[s5] = __shfl(ga[s5][r], srcl, 64);
        bool lo = (u0 < 16);
#pragma unroll
        for (int ns = 0; ns < 4; ++ns) {
          float srel = lo ? bp[ns] : bp[ns + 1];
          float xx = sa[ns][r] + srel;
          if (diag && (ns * 16 + c > wave * 16 + i4)) xx = -1e30f;
          sv[ns][r] = xx;
        }
      }

      // ---- online softmax (DPP reductions, defer-rescale) ----
      float mx[4];
      bool need = false;
#pragma unroll
      for (int r = 0; r < 4; ++r) {
        float m = fmaxf(fmaxf(sv[0][r], sv[1][r]), fmaxf(sv[2][r], sv[3][r]));
        mx[r] = redmax16(m);
        need = need || (mx[r] > mrun[r] + 4.0f);
      }
      if (__ballot(need)) {
#pragma unroll
        for (int r = 0; r < 4; ++r) {
          float mnew = fmaxf(mrun[r], mx[r]);
          float al = fexp2(mrun[r] - mnew);
          mrun[r] = mnew;
          lrun[r] *= al;
#pragma unroll
          for (int ns = 0; ns < 4; ++ns) acc_o[ns][r] *= al;
        }
      }
#pragma unroll
      for (int ns = 0; ns < 4; ++ns)
#pragma unroll
        for (int r = 0; r < 4; ++r)
          sv[ns][r] = fexp2(sv[ns][r] - mrun[r]);
#pragma unroll
      for (int r = 0; r < 4; ++r) {
        float s2 = (sv[0][r] + sv[1][r]) + (sv[2][r] + sv[3][r]);
        lrun[r] += redsum16(s2);
      }

      // ---- P -> LDS (bf16, swizzled, per-wave) ----
      short* Pw = Pl[wave];
#pragma unroll
      for (int ns = 0; ns < 4; ++ns)
#pragma unroll
        for (int r = 0; r < 4; ++r) {
          int row = g * 4 + r;
          int byte = row * 128 + (((ns * 16 + c) * 2) ^ ((row & 7) << 4));
          *reinterpret_cast<short*>(reinterpret_cast<char*>(Pw) + byte) = f2bf(sv[ns][r]);
        }

      // ---- O += P V ----
      __builtin_amdgcn_s_setprio(1);
#pragma unroll
      for (int kk = 0; kk < 2; ++kk) {
        int kbyte = (kk * 32 + g * 8) * 2;
        int byteP = c * 128 + (kbyte ^ ((c & 7) << 4));
        short8 pf = *reinterpret_cast<const short8*>(reinterpret_cast<char*>(Pw) + byteP);
#pragma unroll
        for (int ns = 0; ns < 4; ++ns) {
          int rowV = ns * 16 + c;
          int byteV = rowV * 128 + (kbyte ^ ((rowV & 7) << 4));
          short8 vf = *reinterpret_cast<const short8*>((char*)Vl[sel] + byteV);
          acc_o[ns] = __builtin_amdgcn_mfma_f32_16x16x32_bf16(pf, vf, acc_o[ns], 0, 0, 0);
        }
      }
      __builtin_amdgcn_s_setprio(0);

      __builtin_amdgcn_sched_barrier(0);
      __builtin_amdgcn_s_barrier();
    }

    // ---- epilogue ----
#pragma unroll
    for (int ns = 0; ns < 4; ++ns)
#pragma unroll
      for (int r = 0; r < 4; ++r) {
        int row = g * 4 + r;
        int lg = l0 + wave * 16 + row;
        int d = ns * 16 + c;
        Y[((size_t)bb * LSEQ + lg) * DIM + hh * HS + d] = f2bf(acc_o[ns][r] / lrun[r]);
      }
  };

  process(31 - pair);
  process(pair);
}

// ---------------- launch ----------------

extern "C" void kernel_launch(void* const* d_in, const int* in_sizes, int n_in,
                              void* d_out, int out_size, void* d_ws, size_t ws_size,
                              hipStream_t stream)
{
  const float* x     = (const float*)d_in[0];
  const float* Wqkv  = (const float*)d_in[1];
  const float* bqkv  = (const float*)d_in[2];
  const float* Wproj = (const float*)d_in[3];
  const float* bproj = (const float*)d_in[4];
  const float* Er    = (const float*)d_in[5];

  char* ws = (char*)d_ws;
  short* xb     = (short*)(ws + 0);                       // 4096x1024 bf16 (GEMM1 input)
  short* WqkvT  = (short*)(ws + 8388608);                 // 3072x1024 bf16
  short* WprojT = (short*)(ws + 14680064);                // 1024x1024 bf16
  short* Erb    = (short*)(ws + 16777216);                // 2048x64 bf16
  short* qB     = (short*)(ws + 17039360);                // [32][2048][64] bf16
  short* kB     = (short*)(ws + 25427968);
  short* vTB    = (short*)(ws + 33816576);                // [32][64][2048] bf16 (v transposed)
  short* yB     = (short*)(ws + 42205184);                // 4096x1024 bf16

  prep_kernel<<<dim3(5248), 256, 0, stream>>>(x, Er, Wqkv, Wproj, xb, Erb, WqkvT, WprojT);

  gemm1_kernel<<<dim3(3072 / 128, 4096 / 128), 256, 0, stream>>>(
      xb, WqkvT, bqkv, 4096, 3072, 1024, qB, kB, vTB);

  attn_kernel<<<dim3(512), 256, 0, stream>>>(qB, kB, vTB, Erb, yB);

  gemm2_kernel<<<dim3(1024 / 128, 4096 / 64), 256, 0, stream>>>(
      yB, WprojT, bproj, (float*)d_out);
}